// Round 5
// baseline (53.707 us; speedup 1.0000x reference)
//
#include <hip/hip_runtime.h>
#include <hip/hip_cooperative_groups.h>

namespace cg = cooperative_groups;

#define NB 8
#define NS 2048
#define ND 768
#define ND4 192      // ND/4
#define SC 128       // S-chunks for the v column-sum
#define RPC 16       // rows per chunk = NS/SC
#define GRID 1024    // = SC * NB
#define TPB 256

typedef float f4 __attribute__((ext_vector_type(4)));

// ---------------- shared phase bodies ----------------

// P1: block (c,b) sums rows [c*16, c*16+16) of v[b] -> part4[c*8+b][t]
__device__ __forceinline__ void phase_vpart(const float* __restrict__ v,
                                            float* __restrict__ part,
                                            int c, int b, int t) {
    if (t < ND4) {
        const f4* v4 = (const f4*)v + ((size_t)(b * NS + c * RPC)) * ND4 + t;
        f4 acc = (f4)(0.f);
#pragma unroll
        for (int i = 0; i < RPC; ++i) acc += v4[(size_t)i * ND4];
        ((f4*)part)[((size_t)c * NB + b) * ND4 + t] = acc;
    }
}

// P2 (fused B+C): block (slab,b): reduce part[:,b,:] -> vsum_b (LDS),
// then hvec[b][d] for d in [slab*96, slab*96+96).
__device__ __forceinline__ void phase_bc(const float* __restrict__ part,
                                         const float* __restrict__ fcw,
                                         const float* __restrict__ fcb,
                                         float* __restrict__ hvec,
                                         float* __restrict__ lds_vs, // 768 floats
                                         int slab, int b, int t) {
    if (t < ND4) {
        const f4* p4 = (const f4*)part + (size_t)b * ND4 + t;
        f4 acc = (f4)(0.f);
#pragma unroll 8
        for (int c = 0; c < SC; ++c) acc += p4[(size_t)c * (NB * ND4)];
        ((f4*)lds_vs)[t] = acc;
    }
    __syncthreads();
    const int w = t >> 6, l = t & 63;
#pragma unroll 4
    for (int i = 0; i < 24; ++i) {
        const int d = slab * 96 + w * 24 + i;
        const f4* wrow = (const f4*)(fcw + (size_t)d * ND);
        float s = 0.f;
#pragma unroll
        for (int k = 0; k < 3; ++k) {
            const int e4 = l + k * 64;
            const f4 wv = wrow[e4];
            const f4 vs = ((const f4*)lds_vs)[e4];
            s += wv.x * vs.x + wv.y * vs.y + wv.z * vs.z + wv.w * vs.w;
        }
#pragma unroll
        for (int off = 32; off >= 1; off >>= 1) s += __shfl_xor(s, off, 64);
        if (l == 0) hvec[b * ND + d] = s + fcb[d];
    }
}

// P3: LayerNorm rows [r0, r0+2) for one wave (both rows same batch).
__device__ __forceinline__ void phase_ln2(const float* __restrict__ q,
                                          const float* __restrict__ hvec,
                                          const float* __restrict__ lng,
                                          const float* __restrict__ lnb,
                                          float* __restrict__ out,
                                          int r0, int l) {
    const int b = r0 >> 11;
    const f4* qa = (const f4*)q + (size_t)r0 * ND4;
    const f4* qb = qa + ND4;
    const f4* h4 = (const f4*)hvec + (size_t)b * ND4;

    f4 xa[3], xb[3];
    float sa = 0.f, sqa = 0.f, sb = 0.f, sqb = 0.f;
#pragma unroll
    for (int k = 0; k < 3; ++k) {
        const int e4 = l + k * 64;
        const f4 qva = qa[e4];
        const f4 qvb = qb[e4];
        const f4 hv  = h4[e4];
        const f4 va = qva + hv;
        const f4 vb = qvb + hv;
        xa[k] = va; xb[k] = vb;
        sa  += va.x + va.y + va.z + va.w;
        sqa += va.x * va.x + va.y * va.y + va.z * va.z + va.w * va.w;
        sb  += vb.x + vb.y + vb.z + vb.w;
        sqb += vb.x * vb.x + vb.y * vb.y + vb.z * vb.z + vb.w * vb.w;
    }
#pragma unroll
    for (int off = 32; off >= 1; off >>= 1) {
        sa  += __shfl_xor(sa,  off, 64);
        sqa += __shfl_xor(sqa, off, 64);
        sb  += __shfl_xor(sb,  off, 64);
        sqb += __shfl_xor(sqb, off, 64);
    }
    const float inv = 1.0f / (float)ND;
    const float ma = sa * inv, mb = sb * inv;
    const float ra = rsqrtf(sqa * inv - ma * ma + 1e-5f);
    const float rb = rsqrtf(sqb * inv - mb * mb + 1e-5f);

    f4* oa = (f4*)out + (size_t)r0 * ND4;
    f4* ob = oa + ND4;
#pragma unroll
    for (int k = 0; k < 3; ++k) {
        const int e4 = l + k * 64;
        const f4 gv = ((const f4*)lng)[e4];
        const f4 bv = ((const f4*)lnb)[e4];
        f4 ova, ovb;
        ova.x = (xa[k].x - ma) * ra * gv.x + bv.x;
        ova.y = (xa[k].y - ma) * ra * gv.y + bv.y;
        ova.z = (xa[k].z - ma) * ra * gv.z + bv.z;
        ova.w = (xa[k].w - ma) * ra * gv.w + bv.w;
        ovb.x = (xb[k].x - mb) * rb * gv.x + bv.x;
        ovb.y = (xb[k].y - mb) * rb * gv.y + bv.y;
        ovb.z = (xb[k].z - mb) * rb * gv.z + bv.z;
        ovb.w = (xb[k].w - mb) * rb * gv.w + bv.w;
        __builtin_nontemporal_store(ova, oa + e4);
        __builtin_nontemporal_store(ovb, ob + e4);
    }
}

// ================= 2-sync fused cooperative kernel =================
__global__ __launch_bounds__(TPB, 4) void fused2_kernel(
    const float* __restrict__ q, const float* __restrict__ v,
    const float* __restrict__ fcw, const float* __restrict__ fcb,
    const float* __restrict__ lng, const float* __restrict__ lnb,
    float* __restrict__ part, float* __restrict__ hvec,
    float* __restrict__ out) {
    cg::grid_group grid = cg::this_grid();
    __shared__ float lds_vs[ND];
    const int bb = blockIdx.x;
    const int t = threadIdx.x;

    // ---- P1: v partial column sums (all 1024 blocks)
    phase_vpart(v, part, bb >> 3, bb & 7, t);
    grid.sync();

    // ---- P2: fused reduce+matvec (64 blocks: slab = bb>>3, batch = bb&7)
    if (bb < 64) phase_bc(part, fcw, fcb, hvec, lds_vs, bb >> 3, bb & 7, t);
    grid.sync();

    // ---- P3: LayerNorm, 16 rows/block (4 rows per wave, 2x2)
    {
        const int w = t >> 6, l = t & 63;
#pragma unroll
        for (int j = 0; j < 2; ++j)
            phase_ln2(q, hvec, lng, lnb, out, bb * 16 + w * 4 + j * 2, l);
    }
}

// ================= fallback: 3 kernels (2 gaps) =================
__global__ __launch_bounds__(192) void vpart_kernel(const float* __restrict__ v,
                                                    float* __restrict__ part) {
    phase_vpart(v, part, blockIdx.x, blockIdx.y, threadIdx.x);
}

__global__ __launch_bounds__(TPB) void bc_kernel(const float* __restrict__ part,
                                                 const float* __restrict__ fcw,
                                                 const float* __restrict__ fcb,
                                                 float* __restrict__ hvec) {
    __shared__ float lds_vs[ND];
    phase_bc(part, fcw, fcb, hvec, lds_vs, blockIdx.x >> 3, blockIdx.x & 7, threadIdx.x);
}

__global__ __launch_bounds__(TPB) void ln_kernel(const float* __restrict__ q,
                                                 const float* __restrict__ hvec,
                                                 const float* __restrict__ lng,
                                                 const float* __restrict__ lnb,
                                                 float* __restrict__ out) {
    const int w = threadIdx.x >> 6, l = threadIdx.x & 63;
    phase_ln2(q, hvec, lng, lnb, out, blockIdx.x * 8 + w * 2, l);
}

extern "C" void kernel_launch(void* const* d_in, const int* in_sizes, int n_in,
                              void* d_out, int out_size, void* d_ws, size_t ws_size,
                              hipStream_t stream) {
    // setup_inputs order: q, k, v, mask, fc_w, fc_b, ln_g, ln_b, index, typeAdd_Del
    const float* q   = (const float*)d_in[0];
    const float* v   = (const float*)d_in[2];
    const float* fcw = (const float*)d_in[4];
    const float* fcb = (const float*)d_in[5];
    const float* lng = (const float*)d_in[6];
    const float* lnb = (const float*)d_in[7];
    float* out = (float*)d_out;

    float* part = (float*)d_ws;                 // SC*NB*ND floats = 3 MB
    float* hvec = part + (size_t)SC * NB * ND;  // NB*ND floats

    int blocksPerCU = 0;
    (void)hipOccupancyMaxActiveBlocksPerMultiprocessor(&blocksPerCU,
        (const void*)fused2_kernel, TPB, 0);
    static int numCU = 0;
    if (numCU == 0) {
        hipDeviceProp_t prop;
        (void)hipGetDeviceProperties(&prop, 0);
        numCU = prop.multiProcessorCount;
    }

    if (blocksPerCU * numCU >= GRID) {
        void* args[] = {(void*)&q, (void*)&v, (void*)&fcw, (void*)&fcb,
                        (void*)&lng, (void*)&lnb, (void*)&part, (void*)&hvec,
                        (void*)&out};
        (void)hipLaunchCooperativeKernel((const void*)fused2_kernel, dim3(GRID),
                                         dim3(TPB), args, 0, stream);
    } else {
        vpart_kernel<<<dim3(SC, NB), 192, 0, stream>>>(v, part);
        bc_kernel<<<64, TPB, 0, stream>>>(part, fcw, fcb, hvec);
        ln_kernel<<<(NB * NS) / 8, TPB, 0, stream>>>(q, hvec, lng, lnb, out);
    }
}

// Round 6
// 47.612 us; speedup vs baseline: 1.1280x; 1.1280x over previous
//
#include <hip/hip_runtime.h>

#define NB 8
#define NS 2048
#define ND 768
#define ND4 192      // ND/4
#define SC 128       // S-chunks for the v column-sum
#define RPC 16       // rows per chunk = NS/SC
#define GRID 1024
#define TPB 256

typedef float f4 __attribute__((ext_vector_type(4)));

// ---------- LN compute for one row-pair from preloaded q registers ----------
__device__ __forceinline__ void ln_pair(const f4 qa[3], const f4 qb[3],
                                        const f4* __restrict__ h4,
                                        const float* __restrict__ lng,
                                        const float* __restrict__ lnb,
                                        float* __restrict__ out,
                                        int r0, int l) {
    f4 xa[3], xb[3];
    float sa = 0.f, sqa = 0.f, sb = 0.f, sqb = 0.f;
#pragma unroll
    for (int k = 0; k < 3; ++k) {
        const int e4 = l + k * 64;
        const f4 hv = h4[e4];
        const f4 va = qa[k] + hv;
        const f4 vb = qb[k] + hv;
        xa[k] = va; xb[k] = vb;
        sa  += va.x + va.y + va.z + va.w;
        sqa += va.x * va.x + va.y * va.y + va.z * va.z + va.w * va.w;
        sb  += vb.x + vb.y + vb.z + vb.w;
        sqb += vb.x * vb.x + vb.y * vb.y + vb.z * vb.z + vb.w * vb.w;
    }
#pragma unroll
    for (int off = 32; off >= 1; off >>= 1) {
        sa  += __shfl_xor(sa,  off, 64);
        sqa += __shfl_xor(sqa, off, 64);
        sb  += __shfl_xor(sb,  off, 64);
        sqb += __shfl_xor(sqb, off, 64);
    }
    const float inv = 1.0f / (float)ND;
    const float ma = sa * inv, mb = sb * inv;
    const float ra = rsqrtf(sqa * inv - ma * ma + 1e-5f);
    const float rb = rsqrtf(sqb * inv - mb * mb + 1e-5f);

    f4* oa = (f4*)out + (size_t)r0 * ND4;
    f4* ob = oa + ND4;
#pragma unroll
    for (int k = 0; k < 3; ++k) {
        const int e4 = l + k * 64;
        const f4 gv = ((const f4*)lng)[e4];
        const f4 bv = ((const f4*)lnb)[e4];
        f4 ova, ovb;
        ova.x = (xa[k].x - ma) * ra * gv.x + bv.x;
        ova.y = (xa[k].y - ma) * ra * gv.y + bv.y;
        ova.z = (xa[k].z - ma) * ra * gv.z + bv.z;
        ova.w = (xa[k].w - ma) * ra * gv.w + bv.w;
        ovb.x = (xb[k].x - mb) * rb * gv.x + bv.x;
        ovb.y = (xb[k].y - mb) * rb * gv.y + bv.y;
        ovb.z = (xb[k].z - mb) * rb * gv.z + bv.z;
        ovb.w = (xb[k].w - mb) * rb * gv.w + bv.w;
        __builtin_nontemporal_store(ova, oa + e4);
        __builtin_nontemporal_store(ovb, ob + e4);
    }
}

// ---------- BC body: reduce part[:,b,:] (LDS) then 96 fc_w rows ----------
// 4 rows concurrently per wave via 16-lane groups (kills R5's serial chain).
__device__ __forceinline__ void bc_body(const float* __restrict__ part,
                                        const float* __restrict__ fcw,
                                        const float* __restrict__ fcb,
                                        float* __restrict__ hvec,
                                        float* __restrict__ lds_vs,
                                        int slab, int b, int t) {
    if (t < ND4) {
        const f4* p4 = (const f4*)part + (size_t)b * ND4 + t;
        f4 acc = (f4)(0.f);
#pragma unroll 8
        for (int c = 0; c < SC; ++c) acc += p4[(size_t)c * (NB * ND4)];
        ((f4*)lds_vs)[t] = acc;
    }
    __syncthreads();
    const int w = t >> 6, l = t & 63;
    const int g = l >> 4, li = l & 15;
#pragma unroll
    for (int it = 0; it < 6; ++it) {
        const int d = slab * 96 + w * 24 + it * 4 + g;
        const f4* wrow = (const f4*)(fcw + (size_t)d * ND);
        float s = 0.f;
#pragma unroll
        for (int j = 0; j < 12; ++j) {
            const int e4 = li + j * 16;
            const f4 wv = wrow[e4];
            const f4 vs = ((const f4*)lds_vs)[e4];
            s += wv.x * vs.x + wv.y * vs.y + wv.z * vs.z + wv.w * vs.w;
        }
        s += __shfl_xor(s, 1, 64); s += __shfl_xor(s, 2, 64);
        s += __shfl_xor(s, 4, 64); s += __shfl_xor(s, 8, 64);
        if (li == 0) hvec[b * ND + d] = s + fcb[d];
    }
}

// ================= single persistent pipelined kernel =================
__global__ __launch_bounds__(TPB, 4) void pipe_kernel(
    const float* __restrict__ q, const float* __restrict__ v,
    const float* __restrict__ fcw, const float* __restrict__ fcb,
    const float* __restrict__ lng, const float* __restrict__ lnb,
    float* __restrict__ part, float* __restrict__ hvec,
    int* __restrict__ sync, float* __restrict__ out) {
    const int bb = blockIdx.x, t = threadIdx.x;
    const int w = t >> 6, l = t & 63;
    int* cntA  = sync;
    int* flagH = sync + NB;
    __shared__ float lds_vs[ND];

    // ---- A: block bb sums rows [c*16, c*16+16) of v[b]
    {
        const int c = bb >> 3, b = bb & 7;
        if (t < ND4) {
            const f4* v4 = (const f4*)v + ((size_t)(b * NS + c * RPC)) * ND4 + t;
            f4 acc = (f4)(0.f);
#pragma unroll
            for (int i = 0; i < RPC; ++i) acc += v4[(size_t)i * ND4];
            ((f4*)part)[((size_t)c * NB + b) * ND4 + t] = acc;
        }
        __threadfence();
        __syncthreads();
        if (t == 0)
            __hip_atomic_fetch_add(&cntA[b], 1, __ATOMIC_RELEASE, __HIP_MEMORY_SCOPE_AGENT);
    }

    // ---- BC: blocks 0..63 (slab = bb>>3, batch = bb&7), gated on cntA[b]==128
    if (bb < 64) {
        const int slab = bb >> 3, b = bb & 7;
        if (t == 0)
            while (__hip_atomic_load(&cntA[b], __ATOMIC_ACQUIRE, __HIP_MEMORY_SCOPE_AGENT) < SC) {}
        __syncthreads();
        bc_body(part, fcw, fcb, hvec, lds_vs, slab, b, t);
        __threadfence();
        __syncthreads();
        if (t == 0)
            __hip_atomic_fetch_add(&flagH[b], 1, __ATOMIC_RELEASE, __HIP_MEMORY_SCOPE_AGENT);
    }

    // ---- D: block bb owns global rows [bb*16, bb*16+16); batch = bb>>7.
    {
        const int bd = bb >> 7;
        const int r0 = bb * 16 + w * 4;        // wave's rows r0..r0+3
        // pre-issue q loads for pair 0 (overlaps other blocks' A tail + BC)
        const f4* qa0 = (const f4*)q + (size_t)r0 * ND4;
        const f4* qb0 = qa0 + ND4;
        f4 pqa[3], pqb[3];
#pragma unroll
        for (int k = 0; k < 3; ++k) {
            const int e4 = l + k * 64;
            pqa[k] = qa0[e4];
            pqb[k] = qb0[e4];
        }
        if (t == 0)
            while (__hip_atomic_load(&flagH[bd], __ATOMIC_ACQUIRE, __HIP_MEMORY_SCOPE_AGENT) < 8) {}
        __syncthreads();
        const f4* h4 = (const f4*)hvec + (size_t)bd * ND4;
        ln_pair(pqa, pqb, h4, lng, lnb, out, r0, l);
        // pair 1
        f4 qa1[3], qb1[3];
        const f4* qa1p = qa0 + 2 * ND4;
        const f4* qb1p = qa0 + 3 * ND4;
#pragma unroll
        for (int k = 0; k < 3; ++k) {
            const int e4 = l + k * 64;
            qa1[k] = qa1p[e4];
            qb1[k] = qb1p[e4];
        }
        ln_pair(qa1, qb1, h4, lng, lnb, out, r0 + 2, l);
    }
}

// ================= fallback: 3 kernels (2 gaps), no flags =================
__global__ __launch_bounds__(192) void vpart_kernel(const float* __restrict__ v,
                                                    float* __restrict__ part) {
    const int c = blockIdx.x, b = blockIdx.y, t = threadIdx.x;
    const f4* v4 = (const f4*)v + ((size_t)(b * NS + c * RPC)) * ND4 + t;
    f4 acc = (f4)(0.f);
#pragma unroll
    for (int i = 0; i < RPC; ++i) acc += v4[(size_t)i * ND4];
    ((f4*)part)[((size_t)c * NB + b) * ND4 + t] = acc;
}

__global__ __launch_bounds__(TPB) void bc_kernel(const float* __restrict__ part,
                                                 const float* __restrict__ fcw,
                                                 const float* __restrict__ fcb,
                                                 float* __restrict__ hvec) {
    __shared__ float lds_vs[ND];
    bc_body(part, fcw, fcb, hvec, lds_vs, blockIdx.x >> 3, blockIdx.x & 7, threadIdx.x);
}

__global__ __launch_bounds__(TPB) void ln_kernel(const float* __restrict__ q,
                                                 const float* __restrict__ hvec,
                                                 const float* __restrict__ lng,
                                                 const float* __restrict__ lnb,
                                                 float* __restrict__ out) {
    const int w = threadIdx.x >> 6, l = threadIdx.x & 63;
    const int r0 = blockIdx.x * 16 + w * 4;
    const int bd = r0 >> 11;
    const f4* h4 = (const f4*)hvec + (size_t)bd * ND4;
    const f4* qa0 = (const f4*)q + (size_t)r0 * ND4;
    f4 qa[3], qb[3];
#pragma unroll
    for (int k = 0; k < 3; ++k) {
        const int e4 = l + k * 64;
        qa[k] = qa0[e4];
        qb[k] = qa0[ND4 + e4];
    }
    ln_pair(qa, qb, h4, lng, lnb, out, r0, l);
#pragma unroll
    for (int k = 0; k < 3; ++k) {
        const int e4 = l + k * 64;
        qa[k] = qa0[2 * ND4 + e4];
        qb[k] = qa0[3 * ND4 + e4];
    }
    ln_pair(qa, qb, h4, lng, lnb, out, r0 + 2, l);
}

extern "C" void kernel_launch(void* const* d_in, const int* in_sizes, int n_in,
                              void* d_out, int out_size, void* d_ws, size_t ws_size,
                              hipStream_t stream) {
    // setup_inputs order: q, k, v, mask, fc_w, fc_b, ln_g, ln_b, index, typeAdd_Del
    const float* q   = (const float*)d_in[0];
    const float* v   = (const float*)d_in[2];
    const float* fcw = (const float*)d_in[4];
    const float* fcb = (const float*)d_in[5];
    const float* lng = (const float*)d_in[6];
    const float* lnb = (const float*)d_in[7];
    float* out = (float*)d_out;

    float* part = (float*)d_ws;                     // SC*NB*ND floats = 3 MB
    float* hvec = part + (size_t)SC * NB * ND;      // NB*ND floats
    int*   sync = (int*)(hvec + NB * ND);           // 16 ints

    int blocksPerCU = 0;
    (void)hipOccupancyMaxActiveBlocksPerMultiprocessor(&blocksPerCU,
        (const void*)pipe_kernel, TPB, 0);
    static int numCU = 0;
    if (numCU == 0) {
        hipDeviceProp_t prop;
        (void)hipGetDeviceProperties(&prop, 0);
        numCU = prop.multiProcessorCount;
    }

    if (blocksPerCU * numCU >= GRID) {
        (void)hipMemsetAsync(sync, 0, 2 * NB * sizeof(int), stream);
        void* args[] = {(void*)&q, (void*)&v, (void*)&fcw, (void*)&fcb,
                        (void*)&lng, (void*)&lnb, (void*)&part, (void*)&hvec,
                        (void*)&sync, (void*)&out};
        // cooperative launch only for the co-residency guarantee (no grid.sync inside)
        (void)hipLaunchCooperativeKernel((const void*)pipe_kernel, dim3(GRID),
                                         dim3(TPB), args, 0, stream);
    } else {
        vpart_kernel<<<dim3(SC, NB), 192, 0, stream>>>(v, part);
        bc_kernel<<<64, TPB, 0, stream>>>(part, fcw, fcb, hvec);
        ln_kernel<<<(NB * NS) / 16, TPB, 0, stream>>>(q, hvec, lng, lnb, out);
    }
}

// Round 7
// 47.129 us; speedup vs baseline: 1.1396x; 1.0102x over previous
//
#include <hip/hip_runtime.h>
#include <hip/hip_cooperative_groups.h>

namespace cg = cooperative_groups;

#define NB 8
#define NS 2048
#define ND 768
#define ND4 192      // ND/4
#define SC 128       // S-chunks for the v column-sum
#define RPC 16       // rows per chunk = NS/SC
#define GRID 1024
#define TPB 256

typedef float f4 __attribute__((ext_vector_type(4)));

// ---------- preload 4 q rows (r0..r0+3) into 12 f4 regs ----------
__device__ __forceinline__ void q_preload(const float* __restrict__ q,
                                          f4 qreg[12], int r0, int l) {
    const f4* qb = (const f4*)q + (size_t)r0 * ND4;
#pragma unroll
    for (int r = 0; r < 4; ++r)
#pragma unroll
        for (int k = 0; k < 3; ++k)
            qreg[r * 3 + k] = qb[(size_t)r * ND4 + l + k * 64];
}

// ---------- LN of 4 rows held in registers; h shared across rows ----------
__device__ __forceinline__ void ln_rows4(const f4 qreg[12],
                                         const float* __restrict__ hvec,
                                         const float* __restrict__ lng,
                                         const float* __restrict__ lnb,
                                         float* __restrict__ out,
                                         int b, int r0, int l) {
    const f4* h4 = (const f4*)hvec + (size_t)b * ND4;
    f4 h[3];
#pragma unroll
    for (int k = 0; k < 3; ++k) h[k] = h4[l + k * 64];

    float s[4], sq[4];
#pragma unroll
    for (int r = 0; r < 4; ++r) {
        s[r] = 0.f; sq[r] = 0.f;
#pragma unroll
        for (int k = 0; k < 3; ++k) {
            const f4 x = qreg[r * 3 + k] + h[k];
            s[r]  += x.x + x.y + x.z + x.w;
            sq[r] += x.x * x.x + x.y * x.y + x.z * x.z + x.w * x.w;
        }
    }
#pragma unroll
    for (int off = 32; off >= 1; off >>= 1)
#pragma unroll
        for (int r = 0; r < 4; ++r) {
            s[r]  += __shfl_xor(s[r],  off, 64);
            sq[r] += __shfl_xor(sq[r], off, 64);
        }
    const float inv = 1.0f / (float)ND;
    float mean[4], rstd[4];
#pragma unroll
    for (int r = 0; r < 4; ++r) {
        mean[r] = s[r] * inv;
        rstd[r] = rsqrtf(sq[r] * inv - mean[r] * mean[r] + 1e-5f);
    }
    f4* o4 = (f4*)out + (size_t)r0 * ND4;
#pragma unroll
    for (int k = 0; k < 3; ++k) {
        const int e4 = l + k * 64;
        const f4 gv = ((const f4*)lng)[e4];
        const f4 bv = ((const f4*)lnb)[e4];
#pragma unroll
        for (int r = 0; r < 4; ++r) {
            const f4 x = qreg[r * 3 + k] + h[k];
            f4 ov;
            ov.x = (x.x - mean[r]) * rstd[r] * gv.x + bv.x;
            ov.y = (x.y - mean[r]) * rstd[r] * gv.y + bv.y;
            ov.z = (x.z - mean[r]) * rstd[r] * gv.z + bv.z;
            ov.w = (x.w - mean[r]) * rstd[r] * gv.w + bv.w;
            __builtin_nontemporal_store(ov, o4 + (size_t)r * ND4 + e4);
        }
    }
}

// ---------- BC body: reduce part[:,b,:] (LDS) then 96 fc_w rows ----------
__device__ __forceinline__ void bc_body(const float* __restrict__ part,
                                        const float* __restrict__ fcw,
                                        const float* __restrict__ fcb,
                                        float* __restrict__ hvec,
                                        float* __restrict__ lds_vs,
                                        int slab, int b, int t) {
    if (t < ND4) {
        const f4* p4 = (const f4*)part + (size_t)b * ND4 + t;
        f4 acc = (f4)(0.f);
#pragma unroll 8
        for (int c = 0; c < SC; ++c) acc += p4[(size_t)c * (NB * ND4)];
        ((f4*)lds_vs)[t] = acc;
    }
    __syncthreads();
    const int w = t >> 6, l = t & 63;
    const int g = l >> 4, li = l & 15;
#pragma unroll
    for (int it = 0; it < 6; ++it) {
        const int d = slab * 96 + w * 24 + it * 4 + g;
        const f4* wrow = (const f4*)(fcw + (size_t)d * ND);
        float s = 0.f;
#pragma unroll
        for (int j = 0; j < 12; ++j) {
            const int e4 = li + j * 16;
            const f4 wv = wrow[e4];
            const f4 vs = ((const f4*)lds_vs)[e4];
            s += wv.x * vs.x + wv.y * vs.y + wv.z * vs.z + wv.w * vs.w;
        }
        s += __shfl_xor(s, 1, 64); s += __shfl_xor(s, 2, 64);
        s += __shfl_xor(s, 4, 64); s += __shfl_xor(s, 8, 64);
        if (li == 0) hvec[b * ND + d] = s + fcb[d];
    }
}

// ================= cooperative kernel: q held in registers across syncs =================
__global__ __launch_bounds__(TPB, 4) void qreg_kernel(
    const float* __restrict__ q, const float* __restrict__ v,
    const float* __restrict__ fcw, const float* __restrict__ fcb,
    const float* __restrict__ lng, const float* __restrict__ lnb,
    float* __restrict__ part, float* __restrict__ hvec,
    float* __restrict__ out) {
    cg::grid_group grid = cg::this_grid();
    __shared__ float lds_vs[ND];
    const int bb = blockIdx.x, t = threadIdx.x;
    const int w = t >> 6, l = t & 63;
    const int r0 = bb * 16 + w * 4;            // this wave's 4 LN rows
    const int bd = bb >> 7;                    // LN batch

    f4 qreg[12];

    // ---- Phase 1: v-chunk column sum + q preload (one big streaming phase)
    {
        const int c = bb >> 3, b = bb & 7;
        if (t < ND4) {
            const f4* v4 = (const f4*)v + ((size_t)(b * NS + c * RPC)) * ND4 + t;
            f4 acc = (f4)(0.f);
#pragma unroll
            for (int i = 0; i < RPC; ++i) acc += v4[(size_t)i * ND4];
            ((f4*)part)[((size_t)c * NB + b) * ND4 + t] = acc;
        }
        if (bb >= 64) q_preload(q, qreg, r0, l);   // BC blocks defer (regs dead in BC)
    }
    grid.sync();

    // ---- Phase 2: reduce+matvec (64 blocks)
    if (bb < 64) bc_body(part, fcw, fcb, hvec, lds_vs, bb >> 3, bb & 7, t);
    grid.sync();

    // ---- Phase 3: LN from registers; write-only streaming
    if (bb < 64) q_preload(q, qreg, r0, l);        // 3 MB, L3-hot
    ln_rows4(qreg, hvec, lng, lnb, out, bd, r0, l);
}

// ================= fallback: 3 kernels (2 gaps) =================
__global__ __launch_bounds__(192) void vpart_kernel(const float* __restrict__ v,
                                                    float* __restrict__ part) {
    const int c = blockIdx.x, b = blockIdx.y, t = threadIdx.x;
    const f4* v4 = (const f4*)v + ((size_t)(b * NS + c * RPC)) * ND4 + t;
    f4 acc = (f4)(0.f);
#pragma unroll
    for (int i = 0; i < RPC; ++i) acc += v4[(size_t)i * ND4];
    ((f4*)part)[((size_t)c * NB + b) * ND4 + t] = acc;
}

__global__ __launch_bounds__(TPB) void bc_kernel(const float* __restrict__ part,
                                                 const float* __restrict__ fcw,
                                                 const float* __restrict__ fcb,
                                                 float* __restrict__ hvec) {
    __shared__ float lds_vs[ND];
    bc_body(part, fcw, fcb, hvec, lds_vs, blockIdx.x >> 3, blockIdx.x & 7, threadIdx.x);
}

__global__ __launch_bounds__(TPB) void ln_kernel(const float* __restrict__ q,
                                                 const float* __restrict__ hvec,
                                                 const float* __restrict__ lng,
                                                 const float* __restrict__ lnb,
                                                 float* __restrict__ out) {
    const int w = threadIdx.x >> 6, l = threadIdx.x & 63;
    const int r0 = blockIdx.x * 16 + w * 4;
    const int bd = r0 >> 11;
    f4 qreg[12];
    q_preload(q, qreg, r0, l);
    ln_rows4(qreg, hvec, lng, lnb, out, bd, r0, l);
}

extern "C" void kernel_launch(void* const* d_in, const int* in_sizes, int n_in,
                              void* d_out, int out_size, void* d_ws, size_t ws_size,
                              hipStream_t stream) {
    // setup_inputs order: q, k, v, mask, fc_w, fc_b, ln_g, ln_b, index, typeAdd_Del
    const float* q   = (const float*)d_in[0];
    const float* v   = (const float*)d_in[2];
    const float* fcw = (const float*)d_in[4];
    const float* fcb = (const float*)d_in[5];
    const float* lng = (const float*)d_in[6];
    const float* lnb = (const float*)d_in[7];
    float* out = (float*)d_out;

    float* part = (float*)d_ws;                 // SC*NB*ND floats = 3 MB
    float* hvec = part + (size_t)SC * NB * ND;  // NB*ND floats

    int blocksPerCU = 0;
    (void)hipOccupancyMaxActiveBlocksPerMultiprocessor(&blocksPerCU,
        (const void*)qreg_kernel, TPB, 0);
    static int numCU = 0;
    if (numCU == 0) {
        hipDeviceProp_t prop;
        (void)hipGetDeviceProperties(&prop, 0);
        numCU = prop.multiProcessorCount;
    }

    if (blocksPerCU * numCU >= GRID) {
        void* args[] = {(void*)&q, (void*)&v, (void*)&fcw, (void*)&fcb,
                        (void*)&lng, (void*)&lnb, (void*)&part, (void*)&hvec,
                        (void*)&out};
        (void)hipLaunchCooperativeKernel((const void*)qreg_kernel, dim3(GRID),
                                         dim3(TPB), args, 0, stream);
    } else {
        vpart_kernel<<<dim3(SC, NB), 192, 0, stream>>>(v, part);
        bc_kernel<<<64, TPB, 0, stream>>>(part, fcw, fcb, hvec);
        ln_kernel<<<GRID, TPB, 0, stream>>>(q, hvec, lng, lnb, out);
    }
}